// Round 1
// baseline (787.356 us; speedup 1.0000x reference)
//
#include <hip/hip_runtime.h>
#include <stdint.h>

// Causal dilated conv1d as bf16 MFMA GEMM.
//   out[b,o,t] = sum_{c,kk} W[o, c*4+kk] * x[b, c, t + 8*kk - 24]   (0 if idx<0)
// K-order permuted to kappa = kk*512 + c so that B^T rows are c-contiguous
// after an x transpose:  Xtp[b][tp][c] = (tp<24) ? 0 : bf16(x[b][c][tp-24]).
// GEMM: C[o, n=(b,t)] = sum_kappa Wq[o][kappa] * Xtp[b][t + 8*kk][c].

typedef unsigned short u16;
typedef unsigned int   u32;
typedef __attribute__((ext_vector_type(8))) __bf16 bf16x8;
typedef __attribute__((ext_vector_type(4))) float  floatx4;
typedef __attribute__((ext_vector_type(4))) float  f32x4;

#define NB   16
#define CIN  512
#define COUT 512
#define TT   8192
#define PADT 24
#define TP   (TT + PADT)   /* 8216 rows per batch in Xtp */
#define KTOT 2048          /* CIN * KW */

__device__ __forceinline__ u16 f2bf(float f) {
  // round-to-nearest-even bf16 (inputs are finite random normals)
  u32 u = __builtin_bit_cast(u32, f);
  u += 0x7fffu + ((u >> 16) & 1u);
  return (u16)(u >> 16);
}

__device__ __forceinline__ u32 pack2(float a, float b) {
  return (u32)f2bf(a) | ((u32)f2bf(b) << 16);
}

__device__ __forceinline__ void gl_lds16(const void* g, void* l) {
  // async 16B/lane global->LDS; LDS dest = wave-uniform base + lane*16
  __builtin_amdgcn_global_load_lds((__attribute__((address_space(1))) void*)(g),
                                   (__attribute__((address_space(3))) void*)(l),
                                   16, 0, 0);
}

// ---- Pass 1: transpose + cast  x[b][c][t] -> Xtp[b][24+t][c] -------------
// Register 8x4 micro-transpose; no LDS, no barriers.
// Tile per block: 128 channels x 64 t.  Thread (ct=tid>>4, tq=tid&15) owns
// channels cb=c0+ct*8..+7 at t=t0+tq*4..+3.
// Loads: per instr, 16 lanes x float4 = 256 B contiguous per channel row.
// Stores: uint4 (8 bf16 = 16 B); per instr, 4 same-row lanes form a 64 B
// full-line segment; sibling waves fill adjacent 64 B -> L2 merges lines.
__global__ __launch_bounds__(256) void transpose_cast_k(const float* __restrict__ x,
                                                        u16* __restrict__ xt) {
  const int b   = blockIdx.z;
  const int c0  = blockIdx.y * 128;
  const int t0  = blockIdx.x * 64;
  const int tid = threadIdx.x;

  // fused: zero the 24 pad rows (t-block 0 zeroes its 128-channel slice)
  if (blockIdx.x == 0) {
    for (int idx = tid; idx < 24 * 16; idx += 256) {
      const int row = idx >> 4;        // 0..23
      const int seg = idx & 15;        // 16 x (8 u16 = 16B) per 128-ch slice
      uint4 z; z.x = z.y = z.z = z.w = 0u;
      *(uint4*)(xt + ((size_t)b * TP + row) * CIN + c0 + seg * 8) = z;
    }
  }

  const int tq = tid & 15;
  const int cb = c0 + (tid >> 4) * 8;

  const float* xp = x + ((size_t)(b * CIN + cb)) * TT + t0 + tq * 4;
  f32x4 L[8];
#pragma unroll
  for (int r = 0; r < 8; ++r) L[r] = *(const f32x4*)(xp + (size_t)r * TT);

  u16* op = xt + ((size_t)b * TP + PADT + t0 + tq * 4) * CIN + cb;
#pragma unroll
  for (int j = 0; j < 4; ++j) {
    uint4 v;
    v.x = pack2(L[0][j], L[1][j]);
    v.y = pack2(L[2][j], L[3][j]);
    v.z = pack2(L[4][j], L[5][j]);
    v.w = pack2(L[6][j], L[7][j]);
    *(uint4*)(op + (size_t)j * CIN) = v;
  }
}

// ---- Pass 2: W permute + cast  Wq[o][kk*512+c] = bf16(W[o][c*4+kk]) ------
// One thread per (o,c): float4 load of the 4 taps (contiguous in W), 4 u16
// stores each 128B-contiguous across the wave.
__global__ __launch_bounds__(256) void wperm_k(const float* __restrict__ W,
                                               u16* __restrict__ Wq) {
  const int idx = blockIdx.x * 256 + threadIdx.x;   // o*512 + c, grid=1024
  const int o   = idx >> 9;
  const int c   = idx & 511;
  const f32x4 w = *(const f32x4*)(W + (size_t)idx * 4);
#pragma unroll
  for (int kk = 0; kk < 4; ++kk)
    Wq[((size_t)o * 4 + kk) * 512 + c] = f2bf(w[kk]);
}

// ---- Pass 3: the GEMM (m97 structure: 128x128x32, 16x16x32 bf16 MFMA) ----
// 1D grid, XCD-swizzled: the 4 m-blocks sharing a B strip get ids k,k+8,k+16,k+24
// -> same XCD under round-robin dispatch -> B reuse in that XCD's L2.
__global__ __launch_bounds__(256) void conv_gemm_k(const u16* __restrict__ Wq,
                                                   const u16* __restrict__ Xt,
                                                   float* __restrict__ out) {
  __shared__ u16 As[128 * 32];    // [m][kappa], 64B rows
  __shared__ u16 Bs[128 * 32];    // [n][kappa], 64B rows

  const int tid  = threadIdx.x;
  const int lane = tid & 63;
  const int wave = tid >> 6;

  const int id   = blockIdx.x;              // 0..4095
  const int xcd  = id & 7;
  const int slot = id >> 3;
  const int m0   = (slot & 3) * 128;
  const int nb   = (slot >> 2) * 8 + xcd;   // 0..1023
  const int b    = nb >> 6;                 // 64 n-tiles per batch
  const int t0   = (nb & 63) * 128;

  // staging: each wave stages 32 A-rows and 32 B-rows per K-step (2 issues each)
  const int lr = lane >> 2;                 // row within 16-row group
  const int lo = (lane & 3) * 16;           // byte offset within 64B row
  const char* Ag = (const char*)Wq + ((size_t)(m0 + wave * 32 + lr) * KTOT) * 2 + lo;
  const char* Bg = (const char*)Xt + ((size_t)b * TP + t0 + wave * 32 + lr) * (CIN * 2) + lo;
  char* Al = (char*)As + wave * 2048;
  char* Bl = (char*)Bs + wave * 2048;

  // compute: 2x2 waves, each 64x64 = 4x4 MFMA tiles
  const int wm = (wave >> 1) * 64;
  const int wn = (wave & 1) * 64;
  const char* Af0 = (const char*)As + (wm + (lane & 15)) * 64 + (lane >> 4) * 16;
  const char* Bf0 = (const char*)Bs + (wn + (lane & 15)) * 64 + (lane >> 4) * 16;

  floatx4 acc[4][4];
#pragma unroll
  for (int i = 0; i < 4; ++i)
#pragma unroll
    for (int j = 0; j < 4; ++j) acc[i][j] = (floatx4)(0.0f);

  for (int kt = 0; kt < KTOT / 32; ++kt) {
    const int kap0 = kt * 32;
    const int kk   = kap0 >> 9;             // which of the 4 taps
    const int c0   = kap0 & 511;            // channel offset
    gl_lds16(Ag + (size_t)kt * 64, Al);
    gl_lds16(Ag + (size_t)kt * 64 + 16 * 4096, Al + 1024);
    const size_t boff = (size_t)kk * 8 * (CIN * 2) + c0 * 2;  // +8 rows per tap
    gl_lds16(Bg + boff, Bl);
    gl_lds16(Bg + boff + 16 * (CIN * 2), Bl + 1024);
    __syncthreads();                        // drains vmcnt before LDS reads

    bf16x8 af[4], bff[4];
#pragma unroll
    for (int i = 0; i < 4; ++i) af[i]  = *(const bf16x8*)(Af0 + i * 1024);
#pragma unroll
    for (int j = 0; j < 4; ++j) bff[j] = *(const bf16x8*)(Bf0 + j * 1024);
#pragma unroll
    for (int i = 0; i < 4; ++i)
#pragma unroll
      for (int j = 0; j < 4; ++j)
        acc[i][j] = __builtin_amdgcn_mfma_f32_16x16x32_bf16(af[i], bff[j], acc[i][j], 0, 0, 0);
    __syncthreads();                        // protect LDS for next staging
  }

  // epilogue: D layout col = lane&15, row = (lane>>4)*4 + reg  [m89-verified]
  const int dr = (lane >> 4) * 4;
  const int dc = lane & 15;
  float* outb = out + (size_t)b * COUT * TT;
#pragma unroll
  for (int i = 0; i < 4; ++i) {
#pragma unroll
    for (int j = 0; j < 4; ++j) {
      const int mm = m0 + wm + i * 16 + dr;
      const int nn = t0 + wn + j * 16 + dc;
      float* p = outb + (size_t)mm * TT + nn;
#pragma unroll
      for (int r = 0; r < 4; ++r) p[(size_t)r * TT] = acc[i][j][r];
    }
  }
}

extern "C" void kernel_launch(void* const* d_in, const int* in_sizes, int n_in,
                              void* d_out, int out_size, void* d_ws, size_t ws_size,
                              hipStream_t stream) {
  const float* x = (const float*)d_in[0];   // [16, 512, 8192]
  const float* W = (const float*)d_in[1];   // [512, 2048]
  float* out = (float*)d_out;               // [16, 512, 8192]

  // workspace: Wq bf16 [512][2048] (2 MB) then Xtp bf16 [16][8216][512] (~134.6 MB)
  u16* Wq = (u16*)d_ws;
  u16* Xt = (u16*)d_ws + (1u << 20);

  transpose_cast_k<<<dim3(128, 4, 16), dim3(256), 0, stream>>>(x, Xt);
  wperm_k         <<<dim3(1024),       dim3(256), 0, stream>>>(W, Wq);
  conv_gemm_k     <<<dim3(4096),       dim3(256), 0, stream>>>(Wq, Xt, out);
}